// Round 3
// baseline (482.515 us; speedup 1.0000x reference)
//
#include <hip/hip_runtime.h>
#include <hip/hip_bf16.h>
#include <hip/hip_fp16.h>
#include <stdint.h>

typedef _Float16 half_t;
typedef _Float16 half8 __attribute__((ext_vector_type(8)));
typedef _Float16 half4v __attribute__((ext_vector_type(4)));
typedef float f32x4 __attribute__((ext_vector_type(4)));

#define NN 4096
// ws layout (bytes) — x1 aliases s1 (sequential kernels), y aliases xp.
#define OFF_W1THI  0u
#define OFF_W1TLO  16384u
#define OFF_S1HI   32768u
#define OFF_S1LO   (32768u + 4194304u)
#define OFF_XP0    (32768u + 2u*4194304u)          // 8421376
#define OFF_XP1    (OFF_XP0 + 8388608u)            // 16809984
// total: 25,198,592 bytes

__device__ __forceinline__ float sigmoidf_(float x) { return 1.f / (1.f + __expf(-x)); }
__device__ __forceinline__ float tanhf_(float x)    { return 1.f - 2.f / (__expf(2.f * x) + 1.f); }

// ---- K0: transpose + hi/lo split W1 [96][64] -> W1t [64][96] fp16 pairs
__global__ void prep_w1t(const float* __restrict__ w1,
                         half_t* __restrict__ whi, half_t* __restrict__ wlo) {
    int i = blockIdx.x * 256 + threadIdx.x;
    if (i >= 96 * 64) return;
    int c = i >> 6, d = i & 63;
    float v = w1[i];
    half_t h = (half_t)v;
    whi[d * 96 + c] = h;
    wlo[d * 96 + c] = (half_t)(v - (float)h);
}

// ---- K1: S1t[b][d][n] = sum_c combined[b][n][c] * W1[c][d]  (3-pass fp16 split MFMA)
__global__ __launch_bounds__(256) void k1_gemm(
    const float* __restrict__ inp, const float* __restrict__ hcur,
    const half_t* __restrict__ wthi, const half_t* __restrict__ wtlo,
    half_t* __restrict__ s1hi, half_t* __restrict__ s1lo)
{
    __shared__ half_t Ch[64 * 96], Cl[64 * 96], Wh[64 * 96], Wl[64 * 96];
    const int t = threadIdx.x;
    const int l = t & 63, w = t >> 6, lr = l & 15, lg = l >> 4;
    const int b = blockIdx.x >> 6;
    const int nBase = (blockIdx.x & 63) * 64;

    {   // stage W1t (already split) into LDS
        const uint32_t* sh = (const uint32_t*)wthi;
        const uint32_t* sl = (const uint32_t*)wtlo;
        uint32_t* dh = (uint32_t*)Wh;
        uint32_t* dl = (uint32_t*)Wl;
        for (int i = t; i < 3072; i += 256) { dh[i] = sh[i]; dl[i] = sl[i]; }
    }
    // stage combined = [input | h] rows, split to hi/lo
#pragma unroll
    for (int i = 0; i < 6; ++i) {
        int f4 = t + i * 256;              // 0..1535
        int row = f4 / 24, slot = f4 % 24;
        int n = nBase + row;
        f32x4 v; int c0;
        if (slot < 8) { c0 = slot * 4; v = *(const f32x4*)(inp + ((size_t)b * NN + n) * 32 + c0); }
        else { c0 = 32 + (slot - 8) * 4; v = *(const f32x4*)(hcur + ((size_t)b * NN + n) * 64 + (c0 - 32)); }
#pragma unroll
        for (int jj = 0; jj < 4; ++jj) {
            float x = v[jj];
            half_t hh = (half_t)x;
            Ch[row * 96 + c0 + jj] = hh;
            Cl[row * 96 + c0 + jj] = (half_t)(x - (float)hh);
        }
    }
    __syncthreads();

    const f32x4 z = {0.f, 0.f, 0.f, 0.f};
    f32x4 acc[4] = {z, z, z, z};
#pragma unroll
    for (int kk = 0; kk < 3; ++kk) {
        const int qo = (w * 16 + lr) * 96 + kk * 32 + lg * 8;
        half8 cf_h = *(const half8*)(Ch + qo);
        half8 cf_l = *(const half8*)(Cl + qo);
#pragma unroll
        for (int dt = 0; dt < 4; ++dt) {
            const int po = (dt * 16 + lr) * 96 + kk * 32 + lg * 8;
            half8 wf_h = *(const half8*)(Wh + po);
            half8 wf_l = *(const half8*)(Wl + po);
            acc[dt] = __builtin_amdgcn_mfma_f32_16x16x32_f16(wf_h, cf_h, acc[dt], 0, 0, 0);
            acc[dt] = __builtin_amdgcn_mfma_f32_16x16x32_f16(wf_h, cf_l, acc[dt], 0, 0, 0);
            acc[dt] = __builtin_amdgcn_mfma_f32_16x16x32_f16(wf_l, cf_h, acc[dt], 0, 0, 0);
        }
    }
    const int n = nBase + w * 16 + lr;
#pragma unroll
    for (int dt = 0; dt < 4; ++dt)
#pragma unroll
        for (int j = 0; j < 4; ++j) {
            int d = dt * 16 + lg * 4 + j;
            float v = acc[dt][j];
            half_t hh = (half_t)v;
            size_t o = (size_t)(b * 64 + d) * NN + n;
            s1hi[o] = hh;
            s1lo[o] = (half_t)(v - (float)hh);
        }
}

// ---- K2/K3: adjacency GEMM, fp16 hi/lo 3-pass, mask fused, k-split x2 partials.
// MODE 1: out[(b*64+d)*4096+m] = sum_n (adj*mask)[m,n]*X[b,d,n]   (X=S1)
// MODE 2: out[(b*4096+m)*64+d] = same contraction                  (X=X1)
template<int MODE>
__global__ __launch_bounds__(256) void gemm_adj(
    const float* __restrict__ adj, const float* __restrict__ mask,
    const half_t* __restrict__ xhi, const half_t* __restrict__ xlo,
    float* __restrict__ out0, float* __restrict__ out1)
{
    __shared__ half_t Ah[128 * 64], Al[128 * 64], Xh[64 * 64], Xl[64 * 64];
    const int t = threadIdx.x;
    const int l = t & 63, w = t >> 6, lr = l & 15, lg = l >> 4;
    const int bx = blockIdx.x;
    const int ks = bx & 1;
    const int mb = (bx >> 1) & 31;
    const int b  = bx >> 6;
    const int mBase = mb * 128;
    float* __restrict__ outp = ks ? out1 : out0;

    const half_t* __restrict__ xh_src = xhi + (size_t)b * 64 * NN;
    const half_t* __restrict__ xl_src = xlo + (size_t)b * 64 * NN;

    const f32x4 z = {0.f, 0.f, 0.f, 0.f};
    f32x4 acc[8];
#pragma unroll
    for (int i = 0; i < 8; ++i) acc[i] = z;

    for (int it = 0; it < 32; ++it) {
        const int k0 = (ks * 32 + it) * 64;
        // stage A = adj*mask, split hi/lo, XOR-swizzled rows
#pragma unroll
        for (int i = 0; i < 4; ++i) {
            int c8 = t + i * 256;          // 0..1023
            int row = c8 >> 3, kc = c8 & 7;
            size_t g = (size_t)(mBase + row) * NN + k0 + kc * 8;
            f32x4 a0 = *(const f32x4*)(adj + g);
            f32x4 a1 = *(const f32x4*)(adj + g + 4);
            f32x4 m0 = *(const f32x4*)(mask + g);
            f32x4 m1 = *(const f32x4*)(mask + g + 4);
            half8 hv, lv;
#pragma unroll
            for (int jj = 0; jj < 4; ++jj) {
                float p0 = a0[jj] * m0[jj];
                float p1 = a1[jj] * m1[jj];
                half_t h0 = (half_t)p0, h1 = (half_t)p1;
                hv[jj] = h0; hv[jj + 4] = h1;
                lv[jj] = (half_t)(p0 - (float)h0);
                lv[jj + 4] = (half_t)(p1 - (float)h1);
            }
            int byte = (row * 128 + kc * 16) ^ ((row & 7) << 4);
            *(half8*)((char*)Ah + byte) = hv;
            *(half8*)((char*)Al + byte) = lv;
        }
        // stage X (pre-split hi/lo fp16), same swizzle
#pragma unroll
        for (int i = 0; i < 2; ++i) {
            int c8 = t + i * 256;          // 0..511
            int row = c8 >> 3, kc = c8 & 7;
            size_t g = (size_t)row * NN + k0 + kc * 8;
            int byte = (row * 128 + kc * 16) ^ ((row & 7) << 4);
            *(half8*)((char*)Xh + byte) = *(const half8*)(xh_src + g);
            *(half8*)((char*)Xl + byte) = *(const half8*)(xl_src + g);
        }
        __syncthreads();
#pragma unroll
        for (int kk = 0; kk < 2; ++kk) {
            half8 fxh[4], fxl[4], fah[2], fal[2];
#pragma unroll
            for (int dt = 0; dt < 4; ++dt) {
                int r = dt * 16 + lr;
                int byte = (r * 128 + kk * 64 + lg * 16) ^ ((r & 7) << 4);
                fxh[dt] = *(const half8*)((const char*)Xh + byte);
                fxl[dt] = *(const half8*)((const char*)Xl + byte);
            }
#pragma unroll
            for (int mt = 0; mt < 2; ++mt) {
                int r = w * 32 + mt * 16 + lr;
                int byte = (r * 128 + kk * 64 + lg * 16) ^ ((r & 7) << 4);
                fah[mt] = *(const half8*)((const char*)Ah + byte);
                fal[mt] = *(const half8*)((const char*)Al + byte);
            }
#pragma unroll
            for (int dt = 0; dt < 4; ++dt)
#pragma unroll
                for (int mt = 0; mt < 2; ++mt) {
                    int id = dt * 2 + mt;
                    if (MODE == 1) {
                        acc[id] = __builtin_amdgcn_mfma_f32_16x16x32_f16(fxh[dt], fah[mt], acc[id], 0, 0, 0);
                        acc[id] = __builtin_amdgcn_mfma_f32_16x16x32_f16(fxl[dt], fah[mt], acc[id], 0, 0, 0);
                        acc[id] = __builtin_amdgcn_mfma_f32_16x16x32_f16(fxh[dt], fal[mt], acc[id], 0, 0, 0);
                    } else {
                        acc[id] = __builtin_amdgcn_mfma_f32_16x16x32_f16(fah[mt], fxh[dt], acc[id], 0, 0, 0);
                        acc[id] = __builtin_amdgcn_mfma_f32_16x16x32_f16(fah[mt], fxl[dt], acc[id], 0, 0, 0);
                        acc[id] = __builtin_amdgcn_mfma_f32_16x16x32_f16(fal[mt], fxh[dt], acc[id], 0, 0, 0);
                    }
                }
        }
        __syncthreads();
    }

    if (MODE == 1) {
#pragma unroll
        for (int dt = 0; dt < 4; ++dt)
#pragma unroll
            for (int mt = 0; mt < 2; ++mt) {
                int m = mBase + w * 32 + mt * 16 + lr;
#pragma unroll
                for (int j = 0; j < 4; ++j) {
                    int d = dt * 16 + lg * 4 + j;
                    outp[(size_t)(b * 64 + d) * NN + m] = acc[dt * 2 + mt][j];
                }
            }
    } else {
#pragma unroll
        for (int dt = 0; dt < 4; ++dt)
#pragma unroll
            for (int mt = 0; mt < 2; ++mt) {
                int d = dt * 16 + lr;
#pragma unroll
                for (int j = 0; j < 4; ++j) {
                    int m = mBase + w * 32 + mt * 16 + lg * 4 + j;
                    outp[((size_t)b * NN + m) * 64 + d] = acc[dt * 2 + mt][j];
                }
            }
    }
}

// ---- K2e: x1 = relu(part0+part1+b1); split to fp16 hi/lo
__global__ __launch_bounds__(256) void k2e(
    const float* __restrict__ p0, const float* __restrict__ p1,
    const float* __restrict__ b1,
    half_t* __restrict__ xhi, half_t* __restrict__ xlo)
{
    int i4 = blockIdx.x * 256 + threadIdx.x;   // 0..65535
    for (int r = 0; r < 8; ++r) {
        int idx4 = i4 + r * 65536;             // 0..524287
        size_t e = (size_t)idx4 * 4;
        int d = (int)((e >> 12) & 63);
        f32x4 v = *(const f32x4*)(p0 + e);
        f32x4 u = *(const f32x4*)(p1 + e);
        float bb = b1[d];
        half4v hv, lv;
#pragma unroll
        for (int jj = 0; jj < 4; ++jj) {
            float x = v[jj] + u[jj] + bb;
            x = fmaxf(x, 0.f);
            half_t hh = (half_t)x;
            hv[jj] = hh;
            lv[jj] = (half_t)(x - (float)hh);
        }
        *(half4v*)(xhi + e) = hv;
        *(half4v*)(xlo + e) = lv;
    }
}

// ---- K4: cc = Y@W2 + b2 (fp32, register-blocked) fused with LSTM pointwise
// OUTPUTS ARE FLOAT32 (reference output dtype) — harness compares at bf16 granularity.
__global__ __launch_bounds__(256) void k4_final(
    const float* __restrict__ y0, const float* __restrict__ y1,
    const float* __restrict__ w2, const float* __restrict__ b2,
    const float* __restrict__ ccur,
    float* __restrict__ outh, float* __restrict__ outc)
{
    __shared__ float Yt[64 * 64];   // [d][r] transposed
    __shared__ float Wc[64 * 64];   // [d][u] one gate chunk
    const int t = threadIdx.x;
    const int cb = t & 15, rb = t >> 4;       // cb fastest -> coalesced stores
    const int rowBase = blockIdx.x * 64;

    // stage Yt = (Y0+Y1)^T
#pragma unroll
    for (int i = 0; i < 4; ++i) {
        int id4 = t + i * 256;          // 0..1023
        int r = id4 >> 4, dc = id4 & 15;
        size_t g = (size_t)(rowBase + r) * 64 + dc * 4;
        f32x4 v = *(const f32x4*)(y0 + g);
        f32x4 u = *(const f32x4*)(y1 + g);
#pragma unroll
        for (int jj = 0; jj < 4; ++jj) Yt[(dc * 4 + jj) * 64 + r] = v[jj] + u[jj];
    }

    const f32x4 z = {0.f, 0.f, 0.f, 0.f};
    f32x4 accG[4][4];
#pragma unroll
    for (int g = 0; g < 4; ++g)
#pragma unroll
        for (int r8 = 0; r8 < 4; ++r8) accG[g][r8] = z;

    for (int g = 0; g < 4; ++g) {
        __syncthreads();
#pragma unroll
        for (int i = 0; i < 4; ++i) {
            int id4 = t + i * 256;
            int d = id4 >> 4, uc = id4 & 15;
            f32x4 v = *(const f32x4*)(w2 + (size_t)d * 256 + g * 64 + uc * 4);
            *(f32x4*)(Wc + d * 64 + uc * 4) = v;
        }
        __syncthreads();
        for (int d = 0; d < 64; ++d) {
            f32x4 w4 = *(const f32x4*)(Wc + d * 64 + cb * 4);
            f32x4 y4 = *(const f32x4*)(Yt + d * 64 + rb * 4);
#pragma unroll
            for (int r8 = 0; r8 < 4; ++r8) accG[g][r8] += w4 * y4[r8];
        }
    }

    float b2i[4], b2f[4], b2o[4], b2g[4];
#pragma unroll
    for (int jj = 0; jj < 4; ++jj) {
        b2i[jj] = b2[0 * 64 + cb * 4 + jj];
        b2f[jj] = b2[1 * 64 + cb * 4 + jj];
        b2o[jj] = b2[2 * 64 + cb * 4 + jj];
        b2g[jj] = b2[3 * 64 + cb * 4 + jj];
    }
#pragma unroll
    for (int r8 = 0; r8 < 4; ++r8) {
        int row = rowBase + rb * 4 + r8;
        f32x4 c4 = *(const f32x4*)(ccur + (size_t)row * 64 + cb * 4);
        f32x4 hv, cv;
#pragma unroll
        for (int jj = 0; jj < 4; ++jj) {
            float ii = sigmoidf_(accG[0][r8][jj] + b2i[jj]);
            float ff = sigmoidf_(accG[1][r8][jj] + b2f[jj]);
            float oo = sigmoidf_(accG[2][r8][jj] + b2o[jj]);
            float gg = tanhf_(accG[3][r8][jj] + b2g[jj]);
            float cn = ff * c4[jj] + ii * gg;
            float hn = oo * tanhf_(cn);
            hv[jj] = hn;
            cv[jj] = cn;
        }
        *(f32x4*)(outh + (size_t)row * 64 + cb * 4) = hv;
        *(f32x4*)(outc + (size_t)row * 64 + cb * 4) = cv;
    }
}

extern "C" void kernel_launch(void* const* d_in, const int* in_sizes, int n_in,
                              void* d_out, int out_size, void* d_ws, size_t ws_size,
                              hipStream_t stream) {
    const float* inp   = (const float*)d_in[0];
    const float* hcur  = (const float*)d_in[1];
    const float* ccur  = (const float*)d_in[2];
    const float* adj   = (const float*)d_in[3];
    const float* w1    = (const float*)d_in[4];
    const float* mask1 = (const float*)d_in[5];
    const float* b1    = (const float*)d_in[6];
    const float* w2    = (const float*)d_in[7];
    const float* mask2 = (const float*)d_in[8];
    const float* b2    = (const float*)d_in[9];

    char* ws = (char*)d_ws;
    half_t* w1thi = (half_t*)(ws + OFF_W1THI);
    half_t* w1tlo = (half_t*)(ws + OFF_W1TLO);
    half_t* s1hi  = (half_t*)(ws + OFF_S1HI);
    half_t* s1lo  = (half_t*)(ws + OFF_S1LO);
    half_t* x1hi  = (half_t*)(ws + OFF_S1HI);   // alias: s1 dead after gemm_adj<1>
    half_t* x1lo  = (half_t*)(ws + OFF_S1LO);
    float*  xp0   = (float*)(ws + OFF_XP0);
    float*  xp1   = (float*)(ws + OFF_XP1);
    float*  y0    = (float*)(ws + OFF_XP0);     // alias: xp dead after k2e
    float*  y1    = (float*)(ws + OFF_XP1);

    float* hout = (float*)d_out;                // FLOAT32 outputs
    float* cout = hout + (size_t)8 * 4096 * 64;

    prep_w1t<<<24, 256, 0, stream>>>(w1, w1thi, w1tlo);
    k1_gemm<<<512, 256, 0, stream>>>(inp, hcur, w1thi, w1tlo, s1hi, s1lo);
    gemm_adj<1><<<512, 256, 0, stream>>>(adj, mask1, s1hi, s1lo, xp0, xp1);
    k2e<<<256, 256, 0, stream>>>(xp0, xp1, b1, x1hi, x1lo);
    gemm_adj<2><<<512, 256, 0, stream>>>(adj, mask2, x1hi, x1lo, y0, y1);
    k4_final<<<512, 256, 0, stream>>>(y0, y1, w2, b2, ccur, hout, cout);
}

// Round 4
// 284.023 us; speedup vs baseline: 1.6989x; 1.6989x over previous
//
#include <hip/hip_runtime.h>
#include <hip/hip_bf16.h>
#include <hip/hip_fp16.h>
#include <stdint.h>

typedef _Float16 half_t;
typedef _Float16 half8 __attribute__((ext_vector_type(8)));
typedef _Float16 half4v __attribute__((ext_vector_type(4)));
typedef float f32x4 __attribute__((ext_vector_type(4)));

#define NN 4096
// ws layout (bytes) — x1 aliases s1 (sequential kernels), y aliases xp.
#define OFF_W1THI  0u
#define OFF_W1TLO  16384u
#define OFF_S1HI   32768u
#define OFF_S1LO   (32768u + 4194304u)
#define OFF_XP0    (32768u + 2u*4194304u)          // 8421376
#define OFF_XP1    (OFF_XP0 + 8388608u)            // 16809984
// total: 25,198,592 bytes

__device__ __forceinline__ float sigmoidf_(float x) { return 1.f / (1.f + __expf(-x)); }
__device__ __forceinline__ float tanhf_(float x)    { return 1.f - 2.f / (__expf(2.f * x) + 1.f); }

// ---- K0: transpose + hi/lo split W1 [96][64] -> W1t [64][96] fp16 pairs
__global__ void prep_w1t(const float* __restrict__ w1,
                         half_t* __restrict__ whi, half_t* __restrict__ wlo) {
    int i = blockIdx.x * 256 + threadIdx.x;
    if (i >= 96 * 64) return;
    int c = i >> 6, d = i & 63;
    float v = w1[i];
    half_t h = (half_t)v;
    whi[d * 96 + c] = h;
    wlo[d * 96 + c] = (half_t)(v - (float)h);
}

// ---- K1: S1t[b][d][n] = sum_c combined[b][n][c] * W1[c][d]  (3-pass fp16 split MFMA)
__global__ __launch_bounds__(256) void k1_gemm(
    const float* __restrict__ inp, const float* __restrict__ hcur,
    const half_t* __restrict__ wthi, const half_t* __restrict__ wtlo,
    half_t* __restrict__ s1hi, half_t* __restrict__ s1lo)
{
    __shared__ half_t Ch[64 * 96], Cl[64 * 96], Wh[64 * 96], Wl[64 * 96];
    const int t = threadIdx.x;
    const int l = t & 63, w = t >> 6, lr = l & 15, lg = l >> 4;
    const int b = blockIdx.x >> 6;
    const int nBase = (blockIdx.x & 63) * 64;

    {   // stage W1t (already split) into LDS
        const uint32_t* sh = (const uint32_t*)wthi;
        const uint32_t* sl = (const uint32_t*)wtlo;
        uint32_t* dh = (uint32_t*)Wh;
        uint32_t* dl = (uint32_t*)Wl;
        for (int i = t; i < 3072; i += 256) { dh[i] = sh[i]; dl[i] = sl[i]; }
    }
    // stage combined = [input | h] rows, split to hi/lo
#pragma unroll
    for (int i = 0; i < 6; ++i) {
        int f4 = t + i * 256;              // 0..1535
        int row = f4 / 24, slot = f4 % 24;
        int n = nBase + row;
        f32x4 v; int c0;
        if (slot < 8) { c0 = slot * 4; v = *(const f32x4*)(inp + ((size_t)b * NN + n) * 32 + c0); }
        else { c0 = 32 + (slot - 8) * 4; v = *(const f32x4*)(hcur + ((size_t)b * NN + n) * 64 + (c0 - 32)); }
#pragma unroll
        for (int jj = 0; jj < 4; ++jj) {
            float x = v[jj];
            half_t hh = (half_t)x;
            Ch[row * 96 + c0 + jj] = hh;
            Cl[row * 96 + c0 + jj] = (half_t)(x - (float)hh);
        }
    }
    __syncthreads();

    const f32x4 z = {0.f, 0.f, 0.f, 0.f};
    f32x4 acc[4] = {z, z, z, z};
#pragma unroll
    for (int kk = 0; kk < 3; ++kk) {
        const int qo = (w * 16 + lr) * 96 + kk * 32 + lg * 8;
        half8 cf_h = *(const half8*)(Ch + qo);
        half8 cf_l = *(const half8*)(Cl + qo);
#pragma unroll
        for (int dt = 0; dt < 4; ++dt) {
            const int po = (dt * 16 + lr) * 96 + kk * 32 + lg * 8;
            half8 wf_h = *(const half8*)(Wh + po);
            half8 wf_l = *(const half8*)(Wl + po);
            acc[dt] = __builtin_amdgcn_mfma_f32_16x16x32_f16(wf_h, cf_h, acc[dt], 0, 0, 0);
            acc[dt] = __builtin_amdgcn_mfma_f32_16x16x32_f16(wf_h, cf_l, acc[dt], 0, 0, 0);
            acc[dt] = __builtin_amdgcn_mfma_f32_16x16x32_f16(wf_l, cf_h, acc[dt], 0, 0, 0);
        }
    }
    const int n = nBase + w * 16 + lr;
#pragma unroll
    for (int dt = 0; dt < 4; ++dt)
#pragma unroll
        for (int j = 0; j < 4; ++j) {
            int d = dt * 16 + lg * 4 + j;
            float v = acc[dt][j];
            half_t hh = (half_t)v;
            size_t o = (size_t)(b * 64 + d) * NN + n;
            s1hi[o] = hh;
            s1lo[o] = (half_t)(v - (float)hh);
        }
}

// ---- K2/K3: adjacency GEMM, fp16 hi/lo 3-pass, mask fused, k-split x2 partials.
// MODE 1: out[(b*64+d)*4096+m] = sum_n (adj*mask)[m,n]*X[b,d,n]   (X=S1)
// MODE 2: out[(b*4096+m)*64+d] = same contraction                  (X=X1)
template<int MODE>
__global__ __launch_bounds__(256) void gemm_adj(
    const float* __restrict__ adj, const float* __restrict__ mask,
    const half_t* __restrict__ xhi, const half_t* __restrict__ xlo,
    float* __restrict__ out0, float* __restrict__ out1)
{
    __shared__ half_t Ah[128 * 64], Al[128 * 64], Xh[64 * 64], Xl[64 * 64];
    const int t = threadIdx.x;
    const int l = t & 63, w = t >> 6, lr = l & 15, lg = l >> 4;
    const int bx = blockIdx.x;
    const int ks = bx & 1;
    const int mb = (bx >> 1) & 31;
    const int b  = bx >> 6;
    const int mBase = mb * 128;
    float* __restrict__ outp = ks ? out1 : out0;

    const half_t* __restrict__ xh_src = xhi + (size_t)b * 64 * NN;
    const half_t* __restrict__ xl_src = xlo + (size_t)b * 64 * NN;

    const f32x4 z = {0.f, 0.f, 0.f, 0.f};
    f32x4 acc[8];
#pragma unroll
    for (int i = 0; i < 8; ++i) acc[i] = z;

    for (int it = 0; it < 32; ++it) {
        const int k0 = (ks * 32 + it) * 64;
        // stage A = adj*mask, split hi/lo, XOR-swizzled rows
#pragma unroll
        for (int i = 0; i < 4; ++i) {
            int c8 = t + i * 256;          // 0..1023
            int row = c8 >> 3, kc = c8 & 7;
            size_t g = (size_t)(mBase + row) * NN + k0 + kc * 8;
            f32x4 a0 = *(const f32x4*)(adj + g);
            f32x4 a1 = *(const f32x4*)(adj + g + 4);
            f32x4 m0 = *(const f32x4*)(mask + g);
            f32x4 m1 = *(const f32x4*)(mask + g + 4);
            half8 hv, lv;
#pragma unroll
            for (int jj = 0; jj < 4; ++jj) {
                float p0 = a0[jj] * m0[jj];
                float p1 = a1[jj] * m1[jj];
                half_t h0 = (half_t)p0, h1 = (half_t)p1;
                hv[jj] = h0; hv[jj + 4] = h1;
                lv[jj] = (half_t)(p0 - (float)h0);
                lv[jj + 4] = (half_t)(p1 - (float)h1);
            }
            int byte = (row * 128 + kc * 16) ^ ((row & 7) << 4);
            *(half8*)((char*)Ah + byte) = hv;
            *(half8*)((char*)Al + byte) = lv;
        }
        // stage X (pre-split hi/lo fp16), same swizzle
#pragma unroll
        for (int i = 0; i < 2; ++i) {
            int c8 = t + i * 256;          // 0..511
            int row = c8 >> 3, kc = c8 & 7;
            size_t g = (size_t)row * NN + k0 + kc * 8;
            int byte = (row * 128 + kc * 16) ^ ((row & 7) << 4);
            *(half8*)((char*)Xh + byte) = *(const half8*)(xh_src + g);
            *(half8*)((char*)Xl + byte) = *(const half8*)(xl_src + g);
        }
        __syncthreads();
#pragma unroll
        for (int kk = 0; kk < 2; ++kk) {
            half8 fxh[4], fxl[4], fah[2], fal[2];
#pragma unroll
            for (int dt = 0; dt < 4; ++dt) {
                int r = dt * 16 + lr;
                int byte = (r * 128 + kk * 64 + lg * 16) ^ ((r & 7) << 4);
                fxh[dt] = *(const half8*)((const char*)Xh + byte);
                fxl[dt] = *(const half8*)((const char*)Xl + byte);
            }
#pragma unroll
            for (int mt = 0; mt < 2; ++mt) {
                int r = w * 32 + mt * 16 + lr;
                int byte = (r * 128 + kk * 64 + lg * 16) ^ ((r & 7) << 4);
                fah[mt] = *(const half8*)((const char*)Ah + byte);
                fal[mt] = *(const half8*)((const char*)Al + byte);
            }
#pragma unroll
            for (int dt = 0; dt < 4; ++dt)
#pragma unroll
                for (int mt = 0; mt < 2; ++mt) {
                    int id = dt * 2 + mt;
                    if (MODE == 1) {
                        acc[id] = __builtin_amdgcn_mfma_f32_16x16x32_f16(fxh[dt], fah[mt], acc[id], 0, 0, 0);
                        acc[id] = __builtin_amdgcn_mfma_f32_16x16x32_f16(fxl[dt], fah[mt], acc[id], 0, 0, 0);
                        acc[id] = __builtin_amdgcn_mfma_f32_16x16x32_f16(fxh[dt], fal[mt], acc[id], 0, 0, 0);
                    } else {
                        acc[id] = __builtin_amdgcn_mfma_f32_16x16x32_f16(fah[mt], fxh[dt], acc[id], 0, 0, 0);
                        acc[id] = __builtin_amdgcn_mfma_f32_16x16x32_f16(fah[mt], fxl[dt], acc[id], 0, 0, 0);
                        acc[id] = __builtin_amdgcn_mfma_f32_16x16x32_f16(fal[mt], fxh[dt], acc[id], 0, 0, 0);
                    }
                }
        }
        __syncthreads();
    }

    if (MODE == 1) {
#pragma unroll
        for (int dt = 0; dt < 4; ++dt)
#pragma unroll
            for (int mt = 0; mt < 2; ++mt) {
                int m = mBase + w * 32 + mt * 16 + lr;
#pragma unroll
                for (int j = 0; j < 4; ++j) {
                    int d = dt * 16 + lg * 4 + j;
                    outp[(size_t)(b * 64 + d) * NN + m] = acc[dt * 2 + mt][j];
                }
            }
    } else {
#pragma unroll
        for (int dt = 0; dt < 4; ++dt)
#pragma unroll
            for (int mt = 0; mt < 2; ++mt) {
                int d = dt * 16 + lr;
#pragma unroll
                for (int j = 0; j < 4; ++j) {
                    int m = mBase + w * 32 + mt * 16 + lg * 4 + j;
                    outp[((size_t)b * NN + m) * 64 + d] = acc[dt * 2 + mt][j];
                }
            }
    }
}

// ---- K2e: x1 = relu(part0+part1+b1); split to fp16 hi/lo
__global__ __launch_bounds__(256) void k2e(
    const float* __restrict__ p0, const float* __restrict__ p1,
    const float* __restrict__ b1,
    half_t* __restrict__ xhi, half_t* __restrict__ xlo)
{
    int i4 = blockIdx.x * 256 + threadIdx.x;   // 0..65535
    for (int r = 0; r < 8; ++r) {
        int idx4 = i4 + r * 65536;             // 0..524287
        size_t e = (size_t)idx4 * 4;
        int d = (int)((e >> 12) & 63);
        f32x4 v = *(const f32x4*)(p0 + e);
        f32x4 u = *(const f32x4*)(p1 + e);
        float bb = b1[d];
        half4v hv, lv;
#pragma unroll
        for (int jj = 0; jj < 4; ++jj) {
            float x = v[jj] + u[jj] + bb;
            x = fmaxf(x, 0.f);
            half_t hh = (half_t)x;
            hv[jj] = hh;
            lv[jj] = (half_t)(x - (float)hh);
        }
        *(half4v*)(xhi + e) = hv;
        *(half4v*)(xlo + e) = lv;
    }
}

// ---- K4: cc = Y@W2 + b2 (fp32, register-blocked, FULL W2 in LDS, all acc
// indices compile-time static — no scratch) fused with LSTM pointwise.
// Outputs are float32.
__global__ __launch_bounds__(256) void k4_final(
    const float* __restrict__ y0, const float* __restrict__ y1,
    const float* __restrict__ w2, const float* __restrict__ b2,
    const float* __restrict__ ccur,
    float* __restrict__ outh, float* __restrict__ outc)
{
    __shared__ float Yt[64 * 64];     // [d][r] transposed  (16 KB)
    __shared__ float W2s[64 * 256];   // full W2 [d][4*64]  (64 KB)
    const int t = threadIdx.x;
    const int cb = t & 15, rb = t >> 4;       // cb fastest -> coalesced stores
    const int rowBase = blockIdx.x * 64;

    // stage Yt = (Y0+Y1)^T
#pragma unroll
    for (int i = 0; i < 4; ++i) {
        int id4 = t + i * 256;          // 0..1023
        int r = id4 >> 4, dc = id4 & 15;
        size_t g = (size_t)(rowBase + r) * 64 + dc * 4;
        f32x4 v = *(const f32x4*)(y0 + g);
        f32x4 u = *(const f32x4*)(y1 + g);
#pragma unroll
        for (int jj = 0; jj < 4; ++jj) Yt[(dc * 4 + jj) * 64 + r] = v[jj] + u[jj];
    }
    // stage full W2 (linear copy, f32x4)
#pragma unroll
    for (int i = 0; i < 16; ++i) {
        int id4 = t + i * 256;          // 0..4095
        *(f32x4*)(W2s + id4 * 4) = *(const f32x4*)(w2 + id4 * 4);
    }
    __syncthreads();

    const f32x4 z = {0.f, 0.f, 0.f, 0.f};
    f32x4 accG[4][4];                  // [gate][r8] — static indices only
#pragma unroll
    for (int g = 0; g < 4; ++g)
#pragma unroll
        for (int r8 = 0; r8 < 4; ++r8) accG[g][r8] = z;

    for (int d = 0; d < 64; ++d) {
        f32x4 y4 = *(const f32x4*)(Yt + d * 64 + rb * 4);
#pragma unroll
        for (int g = 0; g < 4; ++g) {
            f32x4 w4 = *(const f32x4*)(W2s + d * 256 + g * 64 + cb * 4);
#pragma unroll
            for (int r8 = 0; r8 < 4; ++r8) accG[g][r8] += w4 * y4[r8];
        }
    }

    float b2i[4], b2f[4], b2o[4], b2g[4];
#pragma unroll
    for (int jj = 0; jj < 4; ++jj) {
        b2i[jj] = b2[0 * 64 + cb * 4 + jj];
        b2f[jj] = b2[1 * 64 + cb * 4 + jj];
        b2o[jj] = b2[2 * 64 + cb * 4 + jj];
        b2g[jj] = b2[3 * 64 + cb * 4 + jj];
    }
#pragma unroll
    for (int r8 = 0; r8 < 4; ++r8) {
        int row = rowBase + rb * 4 + r8;
        f32x4 c4 = *(const f32x4*)(ccur + (size_t)row * 64 + cb * 4);
        f32x4 hv, cv;
#pragma unroll
        for (int jj = 0; jj < 4; ++jj) {
            float ii = sigmoidf_(accG[0][r8][jj] + b2i[jj]);
            float ff = sigmoidf_(accG[1][r8][jj] + b2f[jj]);
            float oo = sigmoidf_(accG[2][r8][jj] + b2o[jj]);
            float gg = tanhf_(accG[3][r8][jj] + b2g[jj]);
            float cn = ff * c4[jj] + ii * gg;
            float hn = oo * tanhf_(cn);
            hv[jj] = hn;
            cv[jj] = cn;
        }
        *(f32x4*)(outh + (size_t)row * 64 + cb * 4) = hv;
        *(f32x4*)(outc + (size_t)row * 64 + cb * 4) = cv;
    }
}

extern "C" void kernel_launch(void* const* d_in, const int* in_sizes, int n_in,
                              void* d_out, int out_size, void* d_ws, size_t ws_size,
                              hipStream_t stream) {
    const float* inp   = (const float*)d_in[0];
    const float* hcur  = (const float*)d_in[1];
    const float* ccur  = (const float*)d_in[2];
    const float* adj   = (const float*)d_in[3];
    const float* w1    = (const float*)d_in[4];
    const float* mask1 = (const float*)d_in[5];
    const float* b1    = (const float*)d_in[6];
    const float* w2    = (const float*)d_in[7];
    const float* mask2 = (const float*)d_in[8];
    const float* b2    = (const float*)d_in[9];

    char* ws = (char*)d_ws;
    half_t* w1thi = (half_t*)(ws + OFF_W1THI);
    half_t* w1tlo = (half_t*)(ws + OFF_W1TLO);
    half_t* s1hi  = (half_t*)(ws + OFF_S1HI);
    half_t* s1lo  = (half_t*)(ws + OFF_S1LO);
    half_t* x1hi  = (half_t*)(ws + OFF_S1HI);   // alias: s1 dead after gemm_adj<1>
    half_t* x1lo  = (half_t*)(ws + OFF_S1LO);
    float*  xp0   = (float*)(ws + OFF_XP0);
    float*  xp1   = (float*)(ws + OFF_XP1);
    float*  y0    = (float*)(ws + OFF_XP0);     // alias: xp dead after k2e
    float*  y1    = (float*)(ws + OFF_XP1);

    float* hout = (float*)d_out;                // FLOAT32 outputs
    float* cout = hout + (size_t)8 * 4096 * 64;

    prep_w1t<<<24, 256, 0, stream>>>(w1, w1thi, w1tlo);
    k1_gemm<<<512, 256, 0, stream>>>(inp, hcur, w1thi, w1tlo, s1hi, s1lo);
    gemm_adj<1><<<512, 256, 0, stream>>>(adj, mask1, s1hi, s1lo, xp0, xp1);
    k2e<<<256, 256, 0, stream>>>(xp0, xp1, b1, x1hi, x1lo);
    gemm_adj<2><<<512, 256, 0, stream>>>(adj, mask2, x1hi, x1lo, y0, y1);
    k4_final<<<512, 256, 0, stream>>>(y0, y1, w2, b2, ccur, hout, cout);
}

// Round 5
// 205.163 us; speedup vs baseline: 2.3519x; 1.3844x over previous
//
#include <hip/hip_runtime.h>
#include <hip/hip_bf16.h>
#include <hip/hip_fp16.h>
#include <stdint.h>

typedef _Float16 half_t;
typedef _Float16 half8 __attribute__((ext_vector_type(8)));
typedef float f32x4 __attribute__((ext_vector_type(4)));

#define NN 4096
// ws layout (bytes). S1/X1: fp16 [64][512][64] hybrid (k-block, j=b*64+d, k-in-block)
// x1 aliases s1 (dead after layer-1 gemm); y aliases xp (dead after k2e).
#define OFF_W1THI  0u
#define OFF_W1TLO  16384u
#define OFF_S1HI   32768u
#define OFF_S1LO   (32768u + 4194304u)
#define OFF_XP0    (32768u + 2u*4194304u)
#define OFF_XP1    (OFF_XP0 + 8388608u)
// total 25,198,592 bytes (same as round-4 proven footprint)

__device__ __forceinline__ float sigmoidf_(float x) { return 1.f / (1.f + __expf(-x)); }
__device__ __forceinline__ float tanhf_(float x)    { return 1.f - 2.f / (__expf(2.f * x) + 1.f); }

// ---- K0: transpose + hi/lo split W1 [96][64] -> W1t [64][96] fp16 pairs
__global__ void prep_w1t(const float* __restrict__ w1,
                         half_t* __restrict__ whi, half_t* __restrict__ wlo) {
    int i = blockIdx.x * 256 + threadIdx.x;
    if (i >= 96 * 64) return;
    int c = i >> 6, d = i & 63;
    float v = w1[i];
    half_t h = (half_t)v;
    whi[d * 96 + c] = h;
    wlo[d * 96 + c] = (half_t)(v - (float)h);
}

// ---- K1: S1[kb][j][kc] (j=b*64+d) = sum_c combined[b][n][c]*W1[c][d], 3-pass fp16
__global__ __launch_bounds__(256) void k1_gemm(
    const float* __restrict__ inp, const float* __restrict__ hcur,
    const half_t* __restrict__ wthi, const half_t* __restrict__ wtlo,
    half_t* __restrict__ s1hi, half_t* __restrict__ s1lo)
{
    __shared__ half_t Ch[64 * 96], Cl[64 * 96], Wh[64 * 96], Wl[64 * 96];
    const int t = threadIdx.x;
    const int l = t & 63, w = t >> 6, lr = l & 15, lg = l >> 4;
    const int b = blockIdx.x >> 6;
    const int kb = blockIdx.x & 63;      // n-tile index = k-block of S1
    const int nBase = kb * 64;

    {   // stage W1t (already split) into LDS
        const uint32_t* sh = (const uint32_t*)wthi;
        const uint32_t* sl = (const uint32_t*)wtlo;
        uint32_t* dh = (uint32_t*)Wh;
        uint32_t* dl = (uint32_t*)Wl;
        for (int i = t; i < 3072; i += 256) { dh[i] = sh[i]; dl[i] = sl[i]; }
    }
    // stage combined = [input | h] rows, split to hi/lo
#pragma unroll
    for (int i = 0; i < 6; ++i) {
        int f4 = t + i * 256;              // 0..1535
        int row = f4 / 24, slot = f4 % 24;
        int n = nBase + row;
        f32x4 v; int c0;
        if (slot < 8) { c0 = slot * 4; v = *(const f32x4*)(inp + ((size_t)b * NN + n) * 32 + c0); }
        else { c0 = 32 + (slot - 8) * 4; v = *(const f32x4*)(hcur + ((size_t)b * NN + n) * 64 + (c0 - 32)); }
#pragma unroll
        for (int jj = 0; jj < 4; ++jj) {
            float x = v[jj];
            half_t hh = (half_t)x;
            Ch[row * 96 + c0 + jj] = hh;
            Cl[row * 96 + c0 + jj] = (half_t)(x - (float)hh);
        }
    }
    __syncthreads();

    const f32x4 z = {0.f, 0.f, 0.f, 0.f};
    f32x4 acc[4] = {z, z, z, z};
#pragma unroll
    for (int kk = 0; kk < 3; ++kk) {
        const int qo = (w * 16 + lr) * 96 + kk * 32 + lg * 8;
        half8 cf_h = *(const half8*)(Ch + qo);
        half8 cf_l = *(const half8*)(Cl + qo);
#pragma unroll
        for (int dt = 0; dt < 4; ++dt) {
            const int po = (dt * 16 + lr) * 96 + kk * 32 + lg * 8;
            half8 wf_h = *(const half8*)(Wh + po);
            half8 wf_l = *(const half8*)(Wl + po);
            acc[dt] = __builtin_amdgcn_mfma_f32_16x16x32_f16(wf_h, cf_h, acc[dt], 0, 0, 0);
            acc[dt] = __builtin_amdgcn_mfma_f32_16x16x32_f16(wf_h, cf_l, acc[dt], 0, 0, 0);
            acc[dt] = __builtin_amdgcn_mfma_f32_16x16x32_f16(wf_l, cf_h, acc[dt], 0, 0, 0);
        }
    }
    // store into hybrid layout: off = (kb*512 + b*64 + d)*64 + kc,  kc = w*16+lr
    const int kc = w * 16 + lr;
#pragma unroll
    for (int dt = 0; dt < 4; ++dt)
#pragma unroll
        for (int j4 = 0; j4 < 4; ++j4) {
            int d = dt * 16 + lg * 4 + j4;
            float v = acc[dt][j4];
            half_t hh = (half_t)v;
            size_t o = ((size_t)kb * 512 + b * 64 + d) * 64 + kc;
            s1hi[o] = hh;
            s1lo[o] = (half_t)(v - (float)hh);
        }
}

// ---- K2/K3 unified: C[m][j] = sum_n (adj*mask)[m,n] * X[n][j]
// M=4096, N(j)=512, K=4096; BM=128, BN=128, BK=64, k-split x2 partials.
// X in hybrid [kb][j][kc] fp16 hi/lo. 1024 threads = 16 waves (4m x 4n).
// grid 256: m-tile fastest -> all (nb,ks) sharing an m-tile land on XCD m%8.
__global__ __launch_bounds__(1024, 4) void gemm_bn(
    const float* __restrict__ adj, const float* __restrict__ mask,
    const half_t* __restrict__ xhi, const half_t* __restrict__ xlo,
    float* __restrict__ out0, float* __restrict__ out1)
{
    __shared__ half_t Ah[128 * 64], Al[128 * 64], Xh[128 * 64], Xl[128 * 64];
    const int t = threadIdx.x;
    const int l = t & 63, w = t >> 6, lr = l & 15, lg = l >> 4;
    const int wm = w >> 2, wn = w & 3;
    const int bx = blockIdx.x;
    const int mt_ = bx & 31, ks = (bx >> 5) & 1, nb = bx >> 6;
    const int mBase = mt_ * 128, jBase = nb * 128;
    float* __restrict__ outp = ks ? out1 : out0;

    const f32x4 z = {0.f, 0.f, 0.f, 0.f};
    f32x4 acc[2][2] = {{z, z}, {z, z}};

    const int srow = t >> 3, skc = t & 7;   // staging slot: 128 rows x 8 chunks
    const int sbyte = (srow * 128 + skc * 16) ^ ((srow & 7) << 4);

    for (int it = 0; it < 32; ++it) {
        const int kb = ks * 32 + it;
        const int k0 = kb * 64;
        {   // A stage: adj*mask -> fp16 hi/lo, swizzled
            size_t g = (size_t)(mBase + srow) * NN + k0 + skc * 8;
            f32x4 a0 = *(const f32x4*)(adj + g);
            f32x4 a1 = *(const f32x4*)(adj + g + 4);
            f32x4 m0 = *(const f32x4*)(mask + g);
            f32x4 m1 = *(const f32x4*)(mask + g + 4);
            half8 hv, lv;
#pragma unroll
            for (int jj = 0; jj < 4; ++jj) {
                float p0 = a0[jj] * m0[jj];
                float p1 = a1[jj] * m1[jj];
                half_t h0 = (half_t)p0, h1 = (half_t)p1;
                hv[jj] = h0; hv[jj + 4] = h1;
                lv[jj] = (half_t)(p0 - (float)h0);
                lv[jj + 4] = (half_t)(p1 - (float)h1);
            }
            *(half8*)((char*)Ah + sbyte) = hv;
            *(half8*)((char*)Al + sbyte) = lv;
        }
        {   // X stage: linear half8 copy from hybrid layout, swizzled
            size_t g = ((size_t)kb * 512 + jBase + srow) * 64 + skc * 8;
            *(half8*)((char*)Xh + sbyte) = *(const half8*)(xhi + g);
            *(half8*)((char*)Xl + sbyte) = *(const half8*)(xlo + g);
        }
        __syncthreads();
#pragma unroll
        for (int kk = 0; kk < 2; ++kk) {
            half8 fa_h[2], fa_l[2], fx_h[2], fx_l[2];
#pragma unroll
            for (int mt = 0; mt < 2; ++mt) {
                int r = wm * 32 + mt * 16 + lr;
                int byte = (r * 128 + kk * 64 + lg * 16) ^ ((r & 7) << 4);
                fa_h[mt] = *(const half8*)((const char*)Ah + byte);
                fa_l[mt] = *(const half8*)((const char*)Al + byte);
            }
#pragma unroll
            for (int nt = 0; nt < 2; ++nt) {
                int r = wn * 32 + nt * 16 + lr;
                int byte = (r * 128 + kk * 64 + lg * 16) ^ ((r & 7) << 4);
                fx_h[nt] = *(const half8*)((const char*)Xh + byte);
                fx_l[nt] = *(const half8*)((const char*)Xl + byte);
            }
#pragma unroll
            for (int mt = 0; mt < 2; ++mt)
#pragma unroll
                for (int nt = 0; nt < 2; ++nt) {
                    acc[mt][nt] = __builtin_amdgcn_mfma_f32_16x16x32_f16(fa_h[mt], fx_h[nt], acc[mt][nt], 0, 0, 0);
                    acc[mt][nt] = __builtin_amdgcn_mfma_f32_16x16x32_f16(fa_l[mt], fx_h[nt], acc[mt][nt], 0, 0, 0);
                    acc[mt][nt] = __builtin_amdgcn_mfma_f32_16x16x32_f16(fa_h[mt], fx_l[nt], acc[mt][nt], 0, 0, 0);
                }
        }
        __syncthreads();
    }
    // C store: row m' = mBase+wm*32+mt*16+lg*4+j4, col j' = jBase+wn*32+nt*16+lr
#pragma unroll
    for (int mt = 0; mt < 2; ++mt)
#pragma unroll
        for (int nt = 0; nt < 2; ++nt) {
            int jcol = jBase + wn * 32 + nt * 16 + lr;
#pragma unroll
            for (int j4 = 0; j4 < 4; ++j4) {
                int mrow = mBase + wm * 32 + mt * 16 + lg * 4 + j4;
                outp[(size_t)mrow * 512 + jcol] = acc[mt][nt][j4];
            }
        }
}

// ---- K2e: x1[kb][j][kc] = relu(xp0+xp1+b1[j&63]) split hi/lo
__global__ __launch_bounds__(256) void k2e(
    const float* __restrict__ p0, const float* __restrict__ p1,
    const float* __restrict__ b1,
    half_t* __restrict__ xhi, half_t* __restrict__ xlo)
{
    int base = blockIdx.x * 256 + threadIdx.x;     // 0..131071
#pragma unroll
    for (int rpt = 0; rpt < 4; ++rpt) {
        int idx4 = base + rpt * 131072;            // 0..524287
        int m = idx4 >> 7, jq = idx4 & 127;
        int j0 = jq * 4, d0 = j0 & 63;
        size_t e = (size_t)m * 512 + j0;
        f32x4 v = *(const f32x4*)(p0 + e);
        f32x4 u = *(const f32x4*)(p1 + e);
        f32x4 bb = *(const f32x4*)(b1 + d0);
        size_t obase = ((size_t)(m >> 6) * 512 + j0) * 64 + (m & 63);
#pragma unroll
        for (int jj = 0; jj < 4; ++jj) {
            float x = v[jj] + u[jj] + bb[jj];
            x = fmaxf(x, 0.f);
            half_t hh = (half_t)x;
            xhi[obase + (size_t)jj * 64] = hh;
            xlo[obase + (size_t)jj * 64] = (half_t)(x - (float)hh);
        }
    }
}

// ---- K4: cc = Y@W2 + b2 (fp32, full W2 in LDS, static acc indices) + LSTM pointwise.
// Y partials in [m][j=b*64+d] layout. Outputs float32 [b][n][64].
__global__ __launch_bounds__(256) void k4_final(
    const float* __restrict__ y0, const float* __restrict__ y1,
    const float* __restrict__ w2, const float* __restrict__ b2,
    const float* __restrict__ ccur,
    float* __restrict__ outh, float* __restrict__ outc)
{
    __shared__ float Yt[64 * 64];     // [d][r] transposed  (16 KB)
    __shared__ float W2s[64 * 256];   // full W2 [d][4*64]  (64 KB)
    const int t = threadIdx.x;
    const int cb = t & 15, rb = t >> 4;
    const int rowBase = blockIdx.x * 64;            // row' = b*4096+m
    const int bIdx = rowBase >> 12, mBase = rowBase & 4095;

    // stage Yt = (Y0+Y1)^T ; source row' -> y[(m)*512 + b*64 + d]
#pragma unroll
    for (int i = 0; i < 4; ++i) {
        int id4 = t + i * 256;          // 0..1023
        int r = id4 >> 4, dc = id4 & 15;
        size_t g = (size_t)(mBase + r) * 512 + bIdx * 64 + dc * 4;
        f32x4 v = *(const f32x4*)(y0 + g);
        f32x4 u = *(const f32x4*)(y1 + g);
#pragma unroll
        for (int jj = 0; jj < 4; ++jj) Yt[(dc * 4 + jj) * 64 + r] = v[jj] + u[jj];
    }
    // stage full W2
#pragma unroll
    for (int i = 0; i < 16; ++i) {
        int id4 = t + i * 256;
        *(f32x4*)(W2s + id4 * 4) = *(const f32x4*)(w2 + id4 * 4);
    }
    __syncthreads();

    const f32x4 z = {0.f, 0.f, 0.f, 0.f};
    f32x4 accG[4][4];
#pragma unroll
    for (int g = 0; g < 4; ++g)
#pragma unroll
        for (int r8 = 0; r8 < 4; ++r8) accG[g][r8] = z;

    for (int d = 0; d < 64; ++d) {
        f32x4 y4 = *(const f32x4*)(Yt + d * 64 + rb * 4);
#pragma unroll
        for (int g = 0; g < 4; ++g) {
            f32x4 w4 = *(const f32x4*)(W2s + d * 256 + g * 64 + cb * 4);
#pragma unroll
            for (int r8 = 0; r8 < 4; ++r8) accG[g][r8] += w4 * y4[r8];
        }
    }

    float b2i[4], b2f[4], b2o[4], b2g[4];
#pragma unroll
    for (int jj = 0; jj < 4; ++jj) {
        b2i[jj] = b2[0 * 64 + cb * 4 + jj];
        b2f[jj] = b2[1 * 64 + cb * 4 + jj];
        b2o[jj] = b2[2 * 64 + cb * 4 + jj];
        b2g[jj] = b2[3 * 64 + cb * 4 + jj];
    }
#pragma unroll
    for (int r8 = 0; r8 < 4; ++r8) {
        int row = rowBase + rb * 4 + r8;
        f32x4 c4 = *(const f32x4*)(ccur + (size_t)row * 64 + cb * 4);
        f32x4 hv, cv;
#pragma unroll
        for (int jj = 0; jj < 4; ++jj) {
            float ii = sigmoidf_(accG[0][r8][jj] + b2i[jj]);
            float ff = sigmoidf_(accG[1][r8][jj] + b2f[jj]);
            float oo = sigmoidf_(accG[2][r8][jj] + b2o[jj]);
            float gg = tanhf_(accG[3][r8][jj] + b2g[jj]);
            float cn = ff * c4[jj] + ii * gg;
            float hn = oo * tanhf_(cn);
            hv[jj] = hn;
            cv[jj] = cn;
        }
        *(f32x4*)(outh + (size_t)row * 64 + cb * 4) = hv;
        *(f32x4*)(outc + (size_t)row * 64 + cb * 4) = cv;
    }
}

extern "C" void kernel_launch(void* const* d_in, const int* in_sizes, int n_in,
                              void* d_out, int out_size, void* d_ws, size_t ws_size,
                              hipStream_t stream) {
    const float* inp   = (const float*)d_in[0];
    const float* hcur  = (const float*)d_in[1];
    const float* ccur  = (const float*)d_in[2];
    const float* adj   = (const float*)d_in[3];
    const float* w1    = (const float*)d_in[4];
    const float* mask1 = (const float*)d_in[5];
    const float* b1    = (const float*)d_in[6];
    const float* w2    = (const float*)d_in[7];
    const float* mask2 = (const float*)d_in[8];
    const float* b2    = (const float*)d_in[9];

    char* ws = (char*)d_ws;
    half_t* w1thi = (half_t*)(ws + OFF_W1THI);
    half_t* w1tlo = (half_t*)(ws + OFF_W1TLO);
    half_t* s1hi  = (half_t*)(ws + OFF_S1HI);
    half_t* s1lo  = (half_t*)(ws + OFF_S1LO);
    half_t* x1hi  = (half_t*)(ws + OFF_S1HI);   // alias: s1 dead after layer-1 gemm
    half_t* x1lo  = (half_t*)(ws + OFF_S1LO);
    float*  xp0   = (float*)(ws + OFF_XP0);
    float*  xp1   = (float*)(ws + OFF_XP1);
    float*  y0    = (float*)(ws + OFF_XP0);     // alias: xp dead after k2e
    float*  y1    = (float*)(ws + OFF_XP1);

    float* hout = (float*)d_out;
    float* cout = hout + (size_t)8 * 4096 * 64;

    prep_w1t<<<24, 256, 0, stream>>>(w1, w1thi, w1tlo);
    k1_gemm<<<512, 256, 0, stream>>>(inp, hcur, w1thi, w1tlo, s1hi, s1lo);
    gemm_bn<<<256, 1024, 0, stream>>>(adj, mask1, s1hi, s1lo, xp0, xp1);
    k2e<<<512, 256, 0, stream>>>(xp0, xp1, b1, x1hi, x1lo);
    gemm_bn<<<256, 1024, 0, stream>>>(adj, mask2, x1hi, x1lo, y0, y1);
    k4_final<<<512, 256, 0, stream>>>(y0, y1, w2, b2, ccur, hout, cout);
}